// Round 1
// baseline (7238.480 us; speedup 1.0000x reference)
//
#include <hip/hip_runtime.h>
#include <cstdint>
#include <cstddef>

// ---------------- problem constants ----------------
#define BB 512
#define TT 96
#define FF 128
#define HH 512
#define BTF 6291456      // B*T*F
#define BH  262144       // B*H

typedef unsigned short ushort_t;
typedef __attribute__((ext_vector_type(8))) short bf16x8;
typedef __attribute__((ext_vector_type(4))) float f32x4;

// ---------------- ws layout (bytes) ----------------
static constexpr size_t OFF_FLAGS = 0;                       // 256 u32 barrier flags
static constexpr size_t OFF_REL   = 1024;                    // 1 u32 release word
static constexpr size_t OFF_DELTA = 4096;                    // bf16 [T*B*F]
static constexpr size_t OFF_MBF   = OFF_DELTA + 12582912;    // bf16 [B*T*F]
static constexpr size_t OFF_ALPHA = OFF_MBF   + 12582912;    // bf16 [T*B*F]
static constexpr size_t OFF_GH    = OFF_ALPHA + 12582912;    // bf16 [T*B*H]
static constexpr size_t OFF_WHBF  = OFF_GH    + 50331648;    // bf16 [F*H]
static constexpr size_t OFF_WFBF  = OFF_WHBF  + 131072;      // bf16 [F*F]
static constexpr size_t OFF_WDXD  = OFF_WFBF  + 32768;       // f32  [F] diag of Wdx
static constexpr size_t OFF_H     = OFF_WDXD  + 512;         // bf16 [2][B*H] ping-pong
static constexpr size_t OFF_HDEC  = OFF_H     + 1048576;     // bf16 [2][B*H]
static constexpr size_t OFF_C     = OFF_HDEC  + 1048576;     // f32  [B*H]
static constexpr size_t OFF_CCBF  = OFF_C     + 1048576;     // bf16 [B*F]
// total ~91.5 MB

// ---------------- helpers ----------------
__device__ __forceinline__ float bf2f(ushort_t u) {
  union { unsigned u; float f; } c; c.u = ((unsigned)u) << 16; return c.f;
}
__device__ __forceinline__ ushort_t f2bf(float f) {
  union { float f; unsigned u; } c; c.f = f;
  unsigned x = c.u;
  unsigned r = (x + 0x7FFFu + ((x >> 16) & 1u)) >> 16;
  return (ushort_t)r;
}
__device__ __forceinline__ float sigm(float v) { return 1.0f / (1.0f + __expf(-v)); }

// ---------------- precompute: weight conversions ----------------
__global__ void k_cvt(const float* __restrict__ Wh, const float* __restrict__ Wf,
                      const float* __restrict__ Wdx, char* __restrict__ ws) {
  ushort_t* whb = (ushort_t*)(ws + OFF_WHBF);
  ushort_t* wfb = (ushort_t*)(ws + OFF_WFBF);
  float* wdxd   = (float*)(ws + OFF_WDXD);
  int i = blockIdx.x * 256 + threadIdx.x;
  if (i < FF * HH) whb[i] = f2bf(Wh[i]);
  if (i < FF * FF) wfb[i] = f2bf(Wf[i]);
  if (i < FF)      wdxd[i] = Wdx[i * (FF + 1)];
}

// ---------------- precompute: delta recurrence + m bf16 ----------------
__global__ void k_prep(const int* __restrict__ mask, char* __restrict__ ws) {
  ushort_t* delta = (ushort_t*)(ws + OFF_DELTA);
  ushort_t* mbf   = (ushort_t*)(ws + OFF_MBF);
  int gtid = blockIdx.x * 256 + threadIdx.x;   // 65536 = B*F
  int b = gtid >> 7, f = gtid & 127;
  const int* mrow = mask + (size_t)b * (TT * FF) + f;
  float dprev = 0.0f;
  for (int t = 0; t < TT; ++t) {
    float d;
    if (t == 0) d = 0.0f;
    else {
      int mp = mrow[(t - 1) * FF];
      d = mp ? 1.0f : dprev + 1.0f;
    }
    dprev = d;
    delta[((size_t)t * BB + b) * FF + f] = f2bf(d);      // integers <=96: exact in bf16
    int mc = mrow[t * FF];
    mbf[(size_t)b * (TT * FF) + t * FF + f] = f2bf((float)mc);
  }
}

// ---------------- precompute: gamma_h = exp(-relu(delta @ Wdh^T + bdh)) ----------------
__global__ __launch_bounds__(256, 4) void k_gh(const float* __restrict__ Wdh,
                                               const float* __restrict__ bdh,
                                               char* __restrict__ ws) {
  __shared__ ushort_t A_lds[64 * 136];
  __shared__ ushort_t B_lds[64 * 136];
  const ushort_t* delta = (const ushort_t*)(ws + OFF_DELTA);
  ushort_t* gh = (ushort_t*)(ws + OFF_GH);
  int tid = threadIdx.x;
  int m0 = blockIdx.x * 64;
  int n0 = blockIdx.y * 64;
  for (int v = tid; v < 1024; v += 256) {
    int row = v >> 4, seg = v & 15;
    *(uint4*)&A_lds[row * 136 + seg * 8] =
        *(const uint4*)(delta + ((size_t)(m0 + row)) * FF + seg * 8);
  }
  for (int v = tid; v < 1024; v += 256) {
    int n = v >> 4, seg = v & 15;
    const float* src = Wdh + (size_t)(n0 + n) * FF + seg * 8;
    ushort_t tmp[8];
#pragma unroll
    for (int j = 0; j < 8; ++j) tmp[j] = f2bf(src[j]);
    *(uint4*)&B_lds[n * 136 + seg * 8] = *(const uint4*)tmp;
  }
  __syncthreads();
  int wave = tid >> 6, lane = tid & 63, quad = lane >> 4, lan = lane & 15;
  int mt = wave;
  f32x4 acc[4];
#pragma unroll
  for (int nt = 0; nt < 4; ++nt) acc[nt] = (f32x4){0.f, 0.f, 0.f, 0.f};
  const ushort_t* ab = &A_lds[(mt * 16 + lan) * 136 + quad * 8];
#pragma unroll
  for (int kk = 0; kk < 4; ++kk) {
    bf16x8 af = *(const bf16x8*)(ab + kk * 32);
#pragma unroll
    for (int nt = 0; nt < 4; ++nt) {
      bf16x8 bfv = *(const bf16x8*)(&B_lds[(nt * 16 + lan) * 136 + kk * 32 + quad * 8]);
      acc[nt] = __builtin_amdgcn_mfma_f32_16x16x32_bf16(af, bfv, acc[nt], 0, 0, 0);
    }
  }
#pragma unroll
  for (int nt = 0; nt < 4; ++nt) {
#pragma unroll
    for (int r = 0; r < 4; ++r) {
      int mg = m0 + mt * 16 + quad * 4 + r;
      int nc = n0 + nt * 16 + lan;
      float v = acc[nt][r] + bdh[nc];
      gh[(size_t)mg * HH + nc] = f2bf(__expf(-fmaxf(v, 0.0f)));
    }
  }
}

// ---------------- precompute: alpha = sigmoid([gamma_x, m] @ Wc^T + bc) ----------------
__global__ __launch_bounds__(256, 4) void k_al(const float* __restrict__ Wc,
                                               const float* __restrict__ bc,
                                               const float* __restrict__ bdx,
                                               char* __restrict__ ws) {
  __shared__ ushort_t A_lds[64 * 136];
  __shared__ ushort_t B_lds[64 * 136];
  const ushort_t* delta = (const ushort_t*)(ws + OFF_DELTA);
  const ushort_t* mbf   = (const ushort_t*)(ws + OFF_MBF);
  const float* wdxd     = (const float*)(ws + OFF_WDXD);
  ushort_t* alpha = (ushort_t*)(ws + OFF_ALPHA);
  int tid = threadIdx.x;
  int m0 = blockIdx.x * 64;
  int n0 = blockIdx.y * 64;
  int wave = tid >> 6, lane = tid & 63, quad = lane >> 4, lan = lane & 15;
  int mt = wave;
  f32x4 acc[4];
#pragma unroll
  for (int nt = 0; nt < 4; ++nt) acc[nt] = (f32x4){0.f, 0.f, 0.f, 0.f};
  for (int c = 0; c < 2; ++c) {
    __syncthreads();
    if (c == 0) {
      for (int v = tid; v < 1024; v += 256) {
        int row = v >> 4, seg = v & 15;
        int mg = m0 + row;
        ushort_t tmp[8];
#pragma unroll
        for (int j = 0; j < 8; ++j) {
          int k = seg * 8 + j;
          float d = bf2f(delta[(size_t)mg * FF + k]);
          float g = __expf(-fmaxf(fmaf(d, wdxd[k], bdx[k]), 0.0f));
          tmp[j] = f2bf(g);
        }
        *(uint4*)&A_lds[row * 136 + seg * 8] = *(const uint4*)tmp;
      }
    } else {
      for (int v = tid; v < 1024; v += 256) {
        int row = v >> 4, seg = v & 15;
        int mg = m0 + row;
        int t = mg >> 9, b = mg & 511;
        *(uint4*)&A_lds[row * 136 + seg * 8] =
            *(const uint4*)(mbf + ((size_t)b * TT + t) * FF + seg * 8);
      }
    }
    for (int v = tid; v < 1024; v += 256) {
      int n = v >> 4, seg = v & 15;
      const float* src = Wc + (size_t)(n0 + n) * 256 + c * 128 + seg * 8;
      ushort_t tmp[8];
#pragma unroll
      for (int j = 0; j < 8; ++j) tmp[j] = f2bf(src[j]);
      *(uint4*)&B_lds[n * 136 + seg * 8] = *(const uint4*)tmp;
    }
    __syncthreads();
    const ushort_t* ab = &A_lds[(mt * 16 + lan) * 136 + quad * 8];
#pragma unroll
    for (int kk = 0; kk < 4; ++kk) {
      bf16x8 af = *(const bf16x8*)(ab + kk * 32);
#pragma unroll
      for (int nt = 0; nt < 4; ++nt) {
        bf16x8 bfv = *(const bf16x8*)(&B_lds[(nt * 16 + lan) * 136 + kk * 32 + quad * 8]);
        acc[nt] = __builtin_amdgcn_mfma_f32_16x16x32_bf16(af, bfv, acc[nt], 0, 0, 0);
      }
    }
  }
#pragma unroll
  for (int nt = 0; nt < 4; ++nt) {
#pragma unroll
    for (int r = 0; r < 4; ++r) {
      int mg = m0 + mt * 16 + quad * 4 + r;
      int nc = n0 + nt * 16 + lan;
      float v = acc[nt][r] + bc[nc];
      alpha[(size_t)mg * FF + nc] = f2bf(sigm(v));
    }
  }
}

// ---------------- grid barrier (flag array + release word; O(1) contention) ----------------
__device__ __forceinline__ void gbar(unsigned* flags, unsigned* rel, unsigned want) {
  __syncthreads();
  if (threadIdx.x == 0) {
    __hip_atomic_store(&flags[blockIdx.x], want, __ATOMIC_RELEASE, __HIP_MEMORY_SCOPE_AGENT);
  }
  if (blockIdx.x == 0) {
    if (threadIdx.x < 256) {
      while (__hip_atomic_load(&flags[threadIdx.x], __ATOMIC_ACQUIRE, __HIP_MEMORY_SCOPE_AGENT) != want)
        __builtin_amdgcn_s_sleep(2);
    }
    __syncthreads();
    if (threadIdx.x == 0)
      __hip_atomic_store(rel, want, __ATOMIC_RELEASE, __HIP_MEMORY_SCOPE_AGENT);
  } else {
    if (threadIdx.x == 0) {
      while (__hip_atomic_load(rel, __ATOMIC_ACQUIRE, __HIP_MEMORY_SCOPE_AGENT) != want)
        __builtin_amdgcn_s_sleep(2);
    }
  }
  __syncthreads();
}

// ---------------- persistent cooperative kernel: 96-step recurrence ----------------
// grid 256 x 512 threads; dyn LDS 141568 B (1 WG/CU).
// LDS: W_lds[64][776] bf16 (gate-weight slice, persistent) | A_lds[64][136] bf16 (K-chunk)
//      gates_lds[64][68] f32 | bias[64] | h_s[1024] f32 | xh_part[512] f32 | xc_s[256] f32
__global__ __launch_bounds__(512, 2) void k_main(
    const float* __restrict__ x, const int* __restrict__ mask,
    const float* __restrict__ bh, const float* __restrict__ bfr,
    const float* __restrict__ Wih, const float* __restrict__ Whh,
    const float* __restrict__ bih, const float* __restrict__ bhh,
    float* __restrict__ out, char* __restrict__ ws) {
  extern __shared__ char smem[];
  ushort_t* W_lds    = (ushort_t*)smem;                 // 99328 B
  ushort_t* A_lds    = (ushort_t*)(smem + 99328);       // 17408 B
  float* gates_lds   = (float*)(smem + 116736);         // 17408 B
  float* bias_lds    = (float*)(smem + 134144);         // 256 B
  float* h_s         = (float*)(smem + 134400);         // 4096 B
  float* xh_part     = (float*)(smem + 138496);         // 2048 B
  float* xc_s        = (float*)(smem + 140544);         // 1024 B

  unsigned* flags = (unsigned*)(ws + OFF_FLAGS);
  unsigned* rel   = (unsigned*)(ws + OFF_REL);
  const ushort_t* alpha = (const ushort_t*)(ws + OFF_ALPHA);
  const ushort_t* gh    = (const ushort_t*)(ws + OFF_GH);
  const ushort_t* mbf   = (const ushort_t*)(ws + OFF_MBF);
  const ushort_t* Wh_bf = (const ushort_t*)(ws + OFF_WHBF);
  const ushort_t* Wf_bf = (const ushort_t*)(ws + OFF_WFBF);
  ushort_t* hws  = (ushort_t*)(ws + OFF_H);
  ushort_t* hdws = (ushort_t*)(ws + OFF_HDEC);
  float* cws     = (float*)(ws + OFF_C);
  ushort_t* ccbf = (ushort_t*)(ws + OFF_CCBF);

  const int tid = threadIdx.x;
  const int wg = blockIdx.x;
  const int bg = wg >> 5, ng = wg & 31;       // phase2: batch-group 0..7, gate-group 0..31
  const int wave = tid >> 6, lane = tid & 63, quad = lane >> 4, lan = lane & 15;
  const int r0 = wg * 2;                      // phase1: rows r0, r0+1

  // ---- init: load gate-weight slice (Wih|Whh rows) into LDS, bf16 ----
  for (int i = tid; i < 64 * 256; i += 512) {
    int n = i >> 8, k = i & 255;
    int r = (n >> 4) * 512 + ng * 16 + (n & 15);
    W_lds[n * 776 + k] = f2bf(Wih[(size_t)r * 256 + k]);
  }
  for (int i = tid; i < 64 * 512; i += 512) {
    int n = i >> 9, k = i & 511;
    int r = (n >> 4) * 512 + ng * 16 + (n & 15);
    W_lds[n * 776 + 256 + k] = f2bf(Whh[(size_t)r * 512 + k]);
  }
  if (tid < 64) {
    int r = (tid >> 4) * 512 + ng * 16 + (tid & 15);
    bias_lds[tid] = bih[r] + bhh[r];
  }
  // zero the state slice this WG owns (ws is poisoned each launch)
  for (int e = tid; e < 1024; e += 512) {
    int bl = e >> 4, jl = e & 15;
    size_t idx = (size_t)(bg * 64 + bl) * HH + ng * 16 + jl;
    hws[idx] = 0;  hws[BH + idx] = 0;
    hdws[idx] = 0; hdws[BH + idx] = 0;
    cws[idx] = 0.0f;
  }
  unsigned ep = 0;
  gbar(flags, rel, ++ep);

  for (int t = 0; t < TT; ++t) {
    // ================= phase 1: x_h -> x_c -> z_h -> c_h -> c_c (2 rows/WG) ============
    const ushort_t* hbuf = hws + (size_t)(t & 1) * BH;
    for (int i = tid; i < 1024; i += 512) h_s[i] = bf2f(hbuf[(size_t)r0 * HH + i]);
    __syncthreads();

    const int bl = tid >> 7, f = tid & 127;   // for combine stage
    float xh = 0.f, xv = 0.f, mv = 0.f;

    if (tid < 256) {                          // dot stage: thread=(kh,f), both rows
      const int fd = tid & 127, kh = tid >> 7;
      const ushort_t* wrow = Wh_bf + (size_t)fd * HH + kh * 256;
      const float* hp0 = h_s + kh * 256;
      const float* hp1 = h_s + 512 + kh * 256;
      float a0 = 0.f, a1 = 0.f;
      for (int k = 0; k < 256; k += 8) {
        uint4 wv = *(const uint4*)(wrow + k);
        const ushort_t* wu = (const ushort_t*)&wv;
#pragma unroll
        for (int j = 0; j < 8; ++j) {
          float w = bf2f(wu[j]);
          a0 = fmaf(hp0[k + j], w, a0);
          a1 = fmaf(hp1[k + j], w, a1);
        }
      }
      xh_part[kh * 256 + fd] = a0;
      xh_part[kh * 256 + 128 + fd] = a1;
    }
    __syncthreads();
    if (tid < 256) {
      xh = xh_part[bl * 128 + f] + xh_part[256 + bl * 128 + f] + bh[f];
      int b = r0 + bl;
      size_t gix = (size_t)b * (TT * FF) + t * FF + f;
      xv = x[gix];
      mv = (float)mask[gix];
      float xcv = fmaf(1.0f - mv, xh, mv * xv);
      xc_s[bl * 128 + f] = xcv;
    }
    __syncthreads();
    if (tid < 256) {
      int b = r0 + bl;
      float accz = 0.f;
      const ushort_t* wfr = Wf_bf + f * 128;
      const float* xcr = xc_s + bl * 128;
      for (int k = 0; k < 128; k += 8) {
        uint4 wv = *(const uint4*)(wfr + k);
        const ushort_t* wu = (const ushort_t*)&wv;
#pragma unroll
        for (int j = 0; j < 8; ++j) accz = fmaf(xcr[k + j], bf2f(wu[j]), accz);
      }
      accz -= xcr[f] * bf2f(wfr[f]);          // off-diagonal mask
      float zh = accz + bfr[f];
      float al = bf2f(alpha[((size_t)t * BB + b) * FF + f]);
      float ch = fmaf(al, zh, (1.0f - al) * xh);
      float cc = fmaf(1.0f - mv, ch, mv * xv);
      size_t ob = (size_t)b * (TT * FF) + t * FF + f;
      out[ob] = cc;
      out[BTF + ob] = ch;
      out[2 * (size_t)BTF + ob] = zh;
      out[3 * (size_t)BTF + ob] = xh;
      ccbf[b * FF + f] = f2bf(cc);
    }
    gbar(flags, rel, ++ep);

    // ================= phase 2: gates GEMM (64x64 tile, K=768) + LSTM update ===========
    const ushort_t* hdec = hdws + (size_t)(t & 1) * BH;
    f32x4 acc0 = (f32x4){0.f, 0.f, 0.f, 0.f};
    f32x4 acc1 = (f32x4){0.f, 0.f, 0.f, 0.f};
    const int mt = wave & 3;
    const int ntA = (wave >> 2) * 2, ntB = ntA + 1;
    for (int c = 0; c < 6; ++c) {
      __syncthreads();
      const ushort_t* src; size_t rstride;
      if (c == 0)      { src = ccbf + (size_t)bg * 64 * FF;                         rstride = FF; }
      else if (c == 1) { src = mbf + (size_t)bg * 64 * (TT * FF) + (size_t)t * FF;  rstride = TT * FF; }
      else             { src = hdec + (size_t)bg * 64 * HH + (size_t)(c - 2) * 128; rstride = HH; }
      for (int v = tid; v < 1024; v += 512) {
        int row = v >> 4, seg = v & 15;
        *(uint4*)&A_lds[row * 136 + seg * 8] = *(const uint4*)(src + row * rstride + seg * 8);
      }
      __syncthreads();
      const ushort_t* ab  = &A_lds[(mt * 16 + lan) * 136 + quad * 8];
      const ushort_t* bbA = &W_lds[(ntA * 16 + lan) * 776 + c * 128 + quad * 8];
      const ushort_t* bbB = &W_lds[(ntB * 16 + lan) * 776 + c * 128 + quad * 8];
#pragma unroll
      for (int kk = 0; kk < 4; ++kk) {
        bf16x8 af = *(const bf16x8*)(ab + kk * 32);
        bf16x8 b0 = *(const bf16x8*)(bbA + kk * 32);
        bf16x8 b1 = *(const bf16x8*)(bbB + kk * 32);
        acc0 = __builtin_amdgcn_mfma_f32_16x16x32_bf16(af, b0, acc0, 0, 0, 0);
        acc1 = __builtin_amdgcn_mfma_f32_16x16x32_bf16(af, b1, acc1, 0, 0, 0);
      }
    }
#pragma unroll
    for (int r = 0; r < 4; ++r) {
      gates_lds[(mt * 16 + quad * 4 + r) * 68 + ntA * 16 + lan] = acc0[r];
      gates_lds[(mt * 16 + quad * 4 + r) * 68 + ntB * 16 + lan] = acc1[r];
    }
    __syncthreads();
    {
      ushort_t* hw  = hws  + (size_t)((t + 1) & 1) * BH;
      ushort_t* hdw = hdws + (size_t)((t + 1) & 1) * BH;
      for (int e = tid; e < 1024; e += 512) {
        int bl2 = e >> 4, jl = e & 15;
        float gi = gates_lds[bl2 * 68 + jl]       + bias_lds[jl];
        float gf = gates_lds[bl2 * 68 + 16 + jl]  + bias_lds[16 + jl];
        float gg = gates_lds[bl2 * 68 + 32 + jl]  + bias_lds[32 + jl];
        float go = gates_lds[bl2 * 68 + 48 + jl]  + bias_lds[48 + jl];
        int b = bg * 64 + bl2, j = ng * 16 + jl;
        size_t idx = (size_t)b * HH + j;
        float co = cws[idx];
        float cn = fmaf(sigm(gf), co, sigm(gi) * tanhf(gg));
        cws[idx] = cn;
        float hn = sigm(go) * tanhf(cn);
        hw[idx] = f2bf(hn);
        float gH = (t < TT - 1) ? bf2f(gh[((size_t)(t + 1) * BB + b) * HH + j]) : 0.0f;
        hdw[idx] = f2bf(hn * gH);   // pre-decayed h for step t+1's gate GEMM
      }
    }
    gbar(flags, rel, ++ep);
  }
}

// ---------------- host ----------------
extern "C" void kernel_launch(void* const* d_in, const int* in_sizes, int n_in,
                              void* d_out, int out_size, void* d_ws, size_t ws_size,
                              hipStream_t stream) {
  (void)in_sizes; (void)n_in; (void)out_size; (void)ws_size;
  const float* x   = (const float*)d_in[0];
  const int*   mask= (const int*)d_in[1];
  const float* Wdh = (const float*)d_in[2];
  const float* bdh = (const float*)d_in[3];
  const float* Wdx = (const float*)d_in[4];
  const float* bdx = (const float*)d_in[5];
  const float* Wh  = (const float*)d_in[6];
  const float* bh  = (const float*)d_in[7];
  const float* Wf  = (const float*)d_in[8];
  const float* bfr = (const float*)d_in[9];
  const float* Wc  = (const float*)d_in[10];
  const float* bc  = (const float*)d_in[11];
  const float* Wih = (const float*)d_in[12];
  const float* Whh = (const float*)d_in[13];
  const float* bih = (const float*)d_in[14];
  const float* bhh = (const float*)d_in[15];
  float* out = (float*)d_out;
  char* ws = (char*)d_ws;

  hipLaunchKernelGGL(k_cvt,  dim3(256), dim3(256), 0, stream, Wh, Wf, Wdx, ws);
  hipLaunchKernelGGL(k_prep, dim3(256), dim3(256), 0, stream, mask, ws);
  hipLaunchKernelGGL(k_gh,   dim3(768, 8), dim3(256), 0, stream, Wdh, bdh, ws);
  hipLaunchKernelGGL(k_al,   dim3(768, 2), dim3(256), 0, stream, Wc, bc, bdx, ws);

  hipFuncSetAttribute((const void*)k_main, hipFuncAttributeMaxDynamicSharedMemorySize, 141568);
  void* args[] = { (void*)&x, (void*)&mask, (void*)&bh, (void*)&bfr, (void*)&Wih, (void*)&Whh,
                   (void*)&bih, (void*)&bhh, (void*)&out, (void*)&ws };
  hipLaunchCooperativeKernel((const void*)k_main, dim3(256), dim3(512), args, 141568, stream);
}

// Round 3
// 2653.631 us; speedup vs baseline: 2.7278x; 2.7278x over previous
//
#include <hip/hip_runtime.h>
#include <cstdint>
#include <cstddef>

// ---------------- problem constants ----------------
#define BB 512
#define TT 96
#define FF 128
#define HH 512
#define BTF 6291456      // B*T*F
#define BH  262144       // B*H

typedef unsigned short ushort_t;
typedef __attribute__((ext_vector_type(8))) short bf16x8;
typedef __attribute__((ext_vector_type(4))) float f32x4;

// ---------------- ws layout (bytes) ----------------
static constexpr size_t OFF_FLAGS = 0;                        // 16 barrier counters, 128 B apart
static constexpr size_t OFF_WDXD  = 2048;                     // f32 [F] diag of Wdx
static constexpr size_t OFF_DELTA = 4096;                     // bf16 [T*B*F]
static constexpr size_t OFF_MBF   = OFF_DELTA + 12582912;     // bf16 [B*T*F]
static constexpr size_t OFF_ALPHA = OFF_MBF   + 12582912;     // bf16 [T*B*F]
static constexpr size_t OFF_GH    = OFF_ALPHA + 12582912;     // bf16 [T*B*H]
static constexpr size_t OFF_H     = OFF_GH    + 50331648;     // f32  [2][B*H] ping-pong
static constexpr size_t OFF_HDEC  = OFF_H     + 2097152;      // bf16 [2][B*H]
static constexpr size_t OFF_CCBF  = OFF_HDEC  + 1048576;      // bf16 [B*F]
// total ~91.4 MB

// ---------------- helpers ----------------
__device__ __forceinline__ float bf2f(ushort_t u) {
  union { unsigned u; float f; } c; c.u = ((unsigned)u) << 16; return c.f;
}
__device__ __forceinline__ ushort_t f2bf(float f) {
  union { float f; unsigned u; } c; c.f = f;
  unsigned x = c.u;
  unsigned r = (x + 0x7FFFu + ((x >> 16) & 1u)) >> 16;
  return (ushort_t)r;
}
__device__ __forceinline__ float lo2f(unsigned p) {
  union { unsigned u; float f; } c; c.u = p << 16; return c.f;
}
__device__ __forceinline__ float hi2f(unsigned p) {
  union { unsigned u; float f; } c; c.u = p & 0xffff0000u; return c.f;
}
__device__ __forceinline__ float sigm(float v) { return 1.0f / (1.0f + __expf(-v)); }

// ---------------- precompute: flag zero + Wdx diag ----------------
__global__ void k_cvt(const float* __restrict__ Wdx, char* __restrict__ ws) {
  int tid = threadIdx.x;
  unsigned* fl = (unsigned*)(ws + OFF_FLAGS);
  fl[tid] = 0; fl[256 + tid] = 0;
  float* wdxd = (float*)(ws + OFF_WDXD);
  if (tid < FF) wdxd[tid] = Wdx[tid * (FF + 1)];
}

// ---------------- precompute: delta recurrence + m bf16 ----------------
__global__ void k_prep(const int* __restrict__ mask, char* __restrict__ ws) {
  ushort_t* delta = (ushort_t*)(ws + OFF_DELTA);
  ushort_t* mbf   = (ushort_t*)(ws + OFF_MBF);
  int gtid = blockIdx.x * 256 + threadIdx.x;   // 65536 = B*F
  int b = gtid >> 7, f = gtid & 127;
  const int* mrow = mask + (size_t)b * (TT * FF) + f;
  float dprev = 0.0f;
  for (int t = 0; t < TT; ++t) {
    float d;
    if (t == 0) d = 0.0f;
    else {
      int mp = mrow[(t - 1) * FF];
      d = mp ? 1.0f : dprev + 1.0f;
    }
    dprev = d;
    delta[((size_t)t * BB + b) * FF + f] = f2bf(d);
    int mc = mrow[t * FF];
    mbf[(size_t)b * (TT * FF) + t * FF + f] = f2bf((float)mc);
  }
}

// ---------------- precompute: gamma_h = exp(-relu(delta @ Wdh^T + bdh)) ----------------
__global__ __launch_bounds__(256, 4) void k_gh(const float* __restrict__ Wdh,
                                               const float* __restrict__ bdh,
                                               char* __restrict__ ws) {
  __shared__ ushort_t A_lds[64 * 136];
  __shared__ ushort_t B_lds[64 * 136];
  const ushort_t* delta = (const ushort_t*)(ws + OFF_DELTA);
  ushort_t* gh = (ushort_t*)(ws + OFF_GH);
  int tid = threadIdx.x;
  int m0 = blockIdx.x * 64;
  int n0 = blockIdx.y * 64;
  for (int v = tid; v < 1024; v += 256) {
    int row = v >> 4, seg = v & 15;
    *(uint4*)&A_lds[row * 136 + seg * 8] =
        *(const uint4*)(delta + ((size_t)(m0 + row)) * FF + seg * 8);
  }
  for (int v = tid; v < 1024; v += 256) {
    int n = v >> 4, seg = v & 15;
    const float* src = Wdh + (size_t)(n0 + n) * FF + seg * 8;
    ushort_t tmp[8];
#pragma unroll
    for (int j = 0; j < 8; ++j) tmp[j] = f2bf(src[j]);
    *(uint4*)&B_lds[n * 136 + seg * 8] = *(const uint4*)tmp;
  }
  __syncthreads();
  int wave = tid >> 6, lane = tid & 63, quad = lane >> 4, lan = lane & 15;
  int mt = wave;
  f32x4 acc[4];
#pragma unroll
  for (int nt = 0; nt < 4; ++nt) acc[nt] = (f32x4){0.f, 0.f, 0.f, 0.f};
  const ushort_t* ab = &A_lds[(mt * 16 + lan) * 136 + quad * 8];
#pragma unroll
  for (int kk = 0; kk < 4; ++kk) {
    bf16x8 af = *(const bf16x8*)(ab + kk * 32);
#pragma unroll
    for (int nt = 0; nt < 4; ++nt) {
      bf16x8 bfv = *(const bf16x8*)(&B_lds[(nt * 16 + lan) * 136 + kk * 32 + quad * 8]);
      acc[nt] = __builtin_amdgcn_mfma_f32_16x16x32_bf16(af, bfv, acc[nt], 0, 0, 0);
    }
  }
#pragma unroll
  for (int nt = 0; nt < 4; ++nt) {
#pragma unroll
    for (int r = 0; r < 4; ++r) {
      int mg = m0 + mt * 16 + quad * 4 + r;
      int nc = n0 + nt * 16 + lan;
      float v = acc[nt][r] + bdh[nc];
      gh[(size_t)mg * HH + nc] = f2bf(__expf(-fmaxf(v, 0.0f)));
    }
  }
}

// ---------------- precompute: alpha = sigmoid([gamma_x, m] @ Wc^T + bc) ----------------
__global__ __launch_bounds__(256, 4) void k_al(const float* __restrict__ Wc,
                                               const float* __restrict__ bc,
                                               const float* __restrict__ bdx,
                                               char* __restrict__ ws) {
  __shared__ ushort_t A_lds[64 * 136];
  __shared__ ushort_t B_lds[64 * 136];
  const ushort_t* delta = (const ushort_t*)(ws + OFF_DELTA);
  const ushort_t* mbf   = (const ushort_t*)(ws + OFF_MBF);
  const float* wdxd     = (const float*)(ws + OFF_WDXD);
  ushort_t* alpha = (ushort_t*)(ws + OFF_ALPHA);
  int tid = threadIdx.x;
  int m0 = blockIdx.x * 64;
  int n0 = blockIdx.y * 64;
  int wave = tid >> 6, lane = tid & 63, quad = lane >> 4, lan = lane & 15;
  int mt = wave;
  f32x4 acc[4];
#pragma unroll
  for (int nt = 0; nt < 4; ++nt) acc[nt] = (f32x4){0.f, 0.f, 0.f, 0.f};
  for (int c = 0; c < 2; ++c) {
    __syncthreads();
    if (c == 0) {
      for (int v = tid; v < 1024; v += 256) {
        int row = v >> 4, seg = v & 15;
        int mg = m0 + row;
        ushort_t tmp[8];
#pragma unroll
        for (int j = 0; j < 8; ++j) {
          int k = seg * 8 + j;
          float d = bf2f(delta[(size_t)mg * FF + k]);
          float g = __expf(-fmaxf(fmaf(d, wdxd[k], bdx[k]), 0.0f));
          tmp[j] = f2bf(g);
        }
        *(uint4*)&A_lds[row * 136 + seg * 8] = *(const uint4*)tmp;
      }
    } else {
      for (int v = tid; v < 1024; v += 256) {
        int row = v >> 4, seg = v & 15;
        int mg = m0 + row;
        int t = mg >> 9, b = mg & 511;
        *(uint4*)&A_lds[row * 136 + seg * 8] =
            *(const uint4*)(mbf + ((size_t)b * TT + t) * FF + seg * 8);
      }
    }
    for (int v = tid; v < 1024; v += 256) {
      int n = v >> 4, seg = v & 15;
      const float* src = Wc + (size_t)(n0 + n) * 256 + c * 128 + seg * 8;
      ushort_t tmp[8];
#pragma unroll
      for (int j = 0; j < 8; ++j) tmp[j] = f2bf(src[j]);
      *(uint4*)&B_lds[n * 136 + seg * 8] = *(const uint4*)tmp;
    }
    __syncthreads();
    const ushort_t* ab = &A_lds[(mt * 16 + lan) * 136 + quad * 8];
#pragma unroll
    for (int kk = 0; kk < 4; ++kk) {
      bf16x8 af = *(const bf16x8*)(ab + kk * 32);
#pragma unroll
      for (int nt = 0; nt < 4; ++nt) {
        bf16x8 bfv = *(const bf16x8*)(&B_lds[(nt * 16 + lan) * 136 + kk * 32 + quad * 8]);
        acc[nt] = __builtin_amdgcn_mfma_f32_16x16x32_bf16(af, bfv, acc[nt], 0, 0, 0);
      }
    }
  }
#pragma unroll
  for (int nt = 0; nt < 4; ++nt) {
#pragma unroll
    for (int r = 0; r < 4; ++r) {
      int mg = m0 + mt * 16 + quad * 4 + r;
      int nc = n0 + nt * 16 + lan;
      float v = acc[nt][r] + bc[nc];
      alpha[(size_t)mg * FF + nc] = f2bf(sigm(v));
    }
  }
}

// ---------------- per-group barrier: relaxed poll, single acquire fence ----------------
// cnt is a dedicated cacheline per (group, barrier-type). 32 WGs per group.
__device__ __forceinline__ void group_barrier(unsigned* cnt, unsigned target) {
  __syncthreads();
  if (threadIdx.x == 0) {
    __hip_atomic_fetch_add(cnt, 1u, __ATOMIC_RELEASE, __HIP_MEMORY_SCOPE_AGENT);
    while (__hip_atomic_load(cnt, __ATOMIC_RELAXED, __HIP_MEMORY_SCOPE_AGENT) < target)
      __builtin_amdgcn_s_sleep(1);
    __builtin_amdgcn_fence(__ATOMIC_ACQUIRE, "agent");
  }
  __syncthreads();
}

// ---------------- persistent cooperative kernel: 96-step recurrence ----------------
// grid 256 x 512 threads; dyn LDS 143616 B (1 WG/CU).
// Groups of 32 WGs by (wg & 7): with round-robin WG->XCD each group is XCD-local.
// Group g owns batch rows 64g..64g+63. Member m = wg>>3:
//   phase1: rows r0 = 64g + 2m (2 rows/WG, Wh/Wf in REGISTERS)
//   phase2: gate col-block ng = m (16 gate cols x 4 types), waves K-split (khalf).
__global__ __launch_bounds__(512, 2) void k_main(
    const float* __restrict__ x, const int* __restrict__ mask,
    const float* __restrict__ Wh, const float* __restrict__ Wf,
    const float* __restrict__ bh, const float* __restrict__ bfr,
    const float* __restrict__ Wih, const float* __restrict__ Whh,
    const float* __restrict__ bih, const float* __restrict__ bhh,
    float* __restrict__ out, char* __restrict__ ws) {
  extern __shared__ char smem[];
  ushort_t* W_lds    = (ushort_t*)smem;                 // 64 x 776 bf16 = 99328 B
  float* gates_lds   = (float*)(smem + 99328);          // 2 x 64 x 68 f32 = 34816 B
  float* bias_lds    = (float*)(smem + 134144);         // 256 B
  float* h_s         = (float*)(smem + 134400);         // 2 x 512 f32 = 4096 B
  float* xh_part     = (float*)(smem + 138496);         // 4 x 256 f32 = 4096 B
  float* xc_s        = (float*)(smem + 142592);         // 256 f32 = 1024 B

  unsigned* cnts = (unsigned*)(ws + OFF_FLAGS);
  const ushort_t* alpha = (const ushort_t*)(ws + OFF_ALPHA);
  const ushort_t* gh    = (const ushort_t*)(ws + OFF_GH);
  const ushort_t* mbf   = (const ushort_t*)(ws + OFF_MBF);
  float*    hws  = (float*)(ws + OFF_H);
  ushort_t* hdws = (ushort_t*)(ws + OFF_HDEC);
  ushort_t* ccbf = (ushort_t*)(ws + OFF_CCBF);

  const int tid  = threadIdx.x;
  const int wg   = blockIdx.x;
  const int g    = wg & 7;          // group == XCD (heuristic)
  const int mwg  = wg >> 3;         // member 0..31
  const int ng   = mwg;             // gate col-block
  const int wave = tid >> 6, lane = tid & 63, quad = lane >> 4, lan = lane & 15;
  const int mt = wave & 3, khalf = wave >> 2;
  const int r0 = g * 64 + mwg * 2;  // phase1 rows
  const int arow = g * 64 + mt * 16 + lan;   // phase2 A-fragment batch row

  unsigned* cntA = cnts + (g * 2 + 0) * 32;
  unsigned* cntB = cnts + (g * 2 + 1) * 32;

  // ---- init: gate-weight slice -> LDS (bf16) ----
  for (int q = tid; q < 4096; q += 512) {           // Wih: 64 n-rows x 256 k
    int n = q >> 6, kq = (q & 63) * 4;
    int r = (n >> 4) * 512 + ng * 16 + (n & 15);
    float4 v = *(const float4*)(Wih + (size_t)r * 256 + kq);
    ushort_t t4[4] = { f2bf(v.x), f2bf(v.y), f2bf(v.z), f2bf(v.w) };
    *(uint2*)&W_lds[n * 776 + kq] = *(const uint2*)t4;
  }
  for (int q = tid; q < 8192; q += 512) {           // Whh: 64 n-rows x 512 k
    int n = q >> 7, kq = (q & 127) * 4;
    int r = (n >> 4) * 512 + ng * 16 + (n & 15);
    float4 v = *(const float4*)(Whh + (size_t)r * 512 + kq);
    ushort_t t4[4] = { f2bf(v.x), f2bf(v.y), f2bf(v.z), f2bf(v.w) };
    *(uint2*)&W_lds[n * 776 + 256 + kq] = *(const uint2*)t4;
  }
  if (tid < 64) {
    int r = (tid >> 4) * 512 + ng * 16 + (tid & 15);
    bias_lds[tid] = bih[r] + bhh[r];
  }

  // ---- init: Wh / Wf slices -> registers (packed bf16 pairs) ----
  const int fdot = tid & 127, kh = tid >> 7;   // dot mapping (all 512 threads)
  unsigned wh_p[64];
  {
    const float* src = Wh + (size_t)fdot * HH + kh * 128;
#pragma unroll
    for (int i = 0; i < 32; ++i) {
      float4 v = *(const float4*)(src + i * 4);
      wh_p[i * 2]     = ((unsigned)f2bf(v.x)) | (((unsigned)f2bf(v.y)) << 16);
      wh_p[i * 2 + 1] = ((unsigned)f2bf(v.z)) | (((unsigned)f2bf(v.w)) << 16);
    }
  }
  unsigned wf_p[16];
  {
    const float* src = Wf + (size_t)fdot * FF + kh * 32;
#pragma unroll
    for (int i = 0; i < 8; ++i) {
      float4 v = *(const float4*)(src + i * 4);
      wf_p[i * 2]     = ((unsigned)f2bf(v.x)) | (((unsigned)f2bf(v.y)) << 16);
      wf_p[i * 2 + 1] = ((unsigned)f2bf(v.z)) | (((unsigned)f2bf(v.w)) << 16);
    }
  }
  float bh_r = 0.f, bfr_r = 0.f, wfd_r = 0.f;
  if (tid < 256) {
    bh_r  = bh[fdot];
    bfr_r = bfr[fdot];
    wfd_r = bf2f(f2bf(Wf[(size_t)fdot * FF + fdot]));  // matches bf16 dot term exactly
  }

  // ---- init: zero owned state slices (buffer 0) + c-state registers ----
  const int b_l = tid >> 3, jl0 = 2 * (tid & 7);     // epilogue mapping
  const int bglob = g * 64 + b_l, j0 = ng * 16 + jl0;
  {
    *(float2*)&hws[(size_t)bglob * HH + j0] = make_float2(0.f, 0.f);
    *(unsigned*)&hdws[(size_t)bglob * HH + j0] = 0u;
  }
  float c_r0 = 0.f, c_r1 = 0.f;

  unsigned epA = 0, epB = 0;
  group_barrier(cntB, 32u * (++epB));

  for (int t = 0; t < TT; ++t) {
    // ---- prefetch step-indexed inputs (no cross-WG deps) ----
    float xv = 0.f, mv = 0.f, al = 0.f;
    if (tid < 256) {
      int bl = tid >> 7;
      int b = r0 + bl;
      size_t gix = (size_t)b * (TT * FF) + (size_t)t * FF + fdot;
      xv = x[gix];
      mv = (float)mask[gix];
      al = bf2f(alpha[((size_t)t * BB + b) * FF + fdot]);
    }
    unsigned gh2 = 0;
    if (t < TT - 1)
      gh2 = *(const unsigned*)&gh[((size_t)(t + 1) * BB + bglob) * HH + j0];

    // ---- phase2a: A-fragments direct from global, waves K-split ----
    const ushort_t* hdec = hdws + (size_t)(t & 1) * BH;
    bf16x8 A0[4], A1[4], A2[4];
    {
      const ushort_t* hrow = hdec + (size_t)arow * HH + quad * 8;
      if (khalf == 0) {
        const ushort_t* mrow = mbf + ((size_t)arow * TT + t) * FF + quad * 8;
#pragma unroll
        for (int kk = 0; kk < 4; ++kk) A0[kk] = *(const bf16x8*)(mrow + kk * 32);
#pragma unroll
        for (int kk = 0; kk < 4; ++kk) A1[kk] = *(const bf16x8*)(hrow + kk * 32);
      } else {
#pragma unroll
        for (int kk = 0; kk < 4; ++kk) A0[kk] = *(const bf16x8*)(hrow + 128 + kk * 32);
#pragma unroll
        for (int kk = 0; kk < 4; ++kk) A1[kk] = *(const bf16x8*)(hrow + 256 + kk * 32);
#pragma unroll
        for (int kk = 0; kk < 4; ++kk) A2[kk] = *(const bf16x8*)(hrow + 384 + kk * 32);
      }
    }

    // ---- stage h(t-1) rows r0, r0+1 into LDS (f32) ----
    const float* hbuf = hws + (size_t)(t & 1) * BH;
    h_s[tid]       = hbuf[(size_t)r0 * HH + tid];
    h_s[512 + tid] = hbuf[(size_t)(r0 + 1) * HH + tid];
    __syncthreads();

    // ---- phase2a MFMA (K-sections not depending on cc) ----
    f32x4 acc[4];
#pragma unroll
    for (int nt = 0; nt < 4; ++nt) acc[nt] = (f32x4){0.f, 0.f, 0.f, 0.f};
    {
      const int w0 = khalf ? 384 : 128;   // A0: m-chunk (128) or hdec c1 (384)
      const int w1 = khalf ? 512 : 256;   // A1: hdec c0 (256) or c2 (512)
#pragma unroll
      for (int kk = 0; kk < 4; ++kk) {
#pragma unroll
        for (int nt = 0; nt < 4; ++nt) {
          bf16x8 bv = *(const bf16x8*)(&W_lds[(nt * 16 + lan) * 776 + w0 + kk * 32 + quad * 8]);
          acc[nt] = __builtin_amdgcn_mfma_f32_16x16x32_bf16(A0[kk], bv, acc[nt], 0, 0, 0);
        }
      }
#pragma unroll
      for (int kk = 0; kk < 4; ++kk) {
#pragma unroll
        for (int nt = 0; nt < 4; ++nt) {
          bf16x8 bv = *(const bf16x8*)(&W_lds[(nt * 16 + lan) * 776 + w1 + kk * 32 + quad * 8]);
          acc[nt] = __builtin_amdgcn_mfma_f32_16x16x32_bf16(A1[kk], bv, acc[nt], 0, 0, 0);
        }
      }
      if (khalf == 1) {
#pragma unroll
        for (int kk = 0; kk < 4; ++kk) {
#pragma unroll
          for (int nt = 0; nt < 4; ++nt) {
            bf16x8 bv = *(const bf16x8*)(&W_lds[(nt * 16 + lan) * 776 + 640 + kk * 32 + quad * 8]);
            acc[nt] = __builtin_amdgcn_mfma_f32_16x16x32_bf16(A2[kk], bv, acc[nt], 0, 0, 0);
          }
        }
        // khalf1 waves are done: publish partial gates now
#pragma unroll
        for (int nt = 0; nt < 4; ++nt)
#pragma unroll
          for (int r = 0; r < 4; ++r)
            gates_lds[(64 + mt * 16 + quad * 4 + r) * 68 + nt * 16 + lan] = acc[nt][r];
      }
    }

    // ---- phase1: xh dot (register Wh, broadcast h from LDS) ----
    float a0 = 0.f, a1 = 0.f;
    {
      const float* h0p = h_s + kh * 128;
      const float* h1p = h_s + 512 + kh * 128;
#pragma unroll
      for (int i2 = 0; i2 < 16; ++i2) {
        float hb0[8], hb1[8];
        *(float4*)&hb0[0] = *(const float4*)&h0p[i2 * 8];
        *(float4*)&hb0[4] = *(const float4*)&h0p[i2 * 8 + 4];
        *(float4*)&hb1[0] = *(const float4*)&h1p[i2 * 8];
        *(float4*)&hb1[4] = *(const float4*)&h1p[i2 * 8 + 4];
#pragma unroll
        for (int j = 0; j < 4; ++j) {
          unsigned wp = wh_p[i2 * 4 + j];
          float w0 = lo2f(wp), w1 = hi2f(wp);
          a0 = fmaf(w0, hb0[2 * j], a0);
          a0 = fmaf(w1, hb0[2 * j + 1], a0);
          a1 = fmaf(w0, hb1[2 * j], a1);
          a1 = fmaf(w1, hb1[2 * j + 1], a1);
        }
      }
      xh_part[kh * 256 + fdot]       = a0;
      xh_part[kh * 256 + 128 + fdot] = a1;
    }
    __syncthreads();

    float xh_r = 0.f;
    if (tid < 256) {
      int bl = tid >> 7;
      xh_r = xh_part[bl * 128 + fdot] + xh_part[256 + bl * 128 + fdot]
           + xh_part[512 + bl * 128 + fdot] + xh_part[768 + bl * 128 + fdot] + bh_r;
      float xcv = fmaf(1.0f - mv, xh_r, mv * xv);
      xc_s[bl * 128 + fdot] = xcv;
    }
    __syncthreads();

    // ---- z_h dot (register Wf, K split 4 ways) ----
    {
      float z0 = 0.f, z1 = 0.f;
      const float* x0p = xc_s + kh * 32;
      const float* x1p = xc_s + 128 + kh * 32;
#pragma unroll
      for (int i2 = 0; i2 < 4; ++i2) {
        float xb0[8], xb1[8];
        *(float4*)&xb0[0] = *(const float4*)&x0p[i2 * 8];
        *(float4*)&xb0[4] = *(const float4*)&x0p[i2 * 8 + 4];
        *(float4*)&xb1[0] = *(const float4*)&x1p[i2 * 8];
        *(float4*)&xb1[4] = *(const float4*)&x1p[i2 * 8 + 4];
#pragma unroll
        for (int j = 0; j < 4; ++j) {
          unsigned wp = wf_p[i2 * 4 + j];
          float w0 = lo2f(wp), w1 = hi2f(wp);
          z0 = fmaf(w0, xb0[2 * j], z0);
          z0 = fmaf(w1, xb0[2 * j + 1], z0);
          z1 = fmaf(w0, xb1[2 * j], z1);
          z1 = fmaf(w1, xb1[2 * j + 1], z1);
        }
      }
      xh_part[kh * 256 + fdot]       = z0;
      xh_part[kh * 256 + 128 + fdot] = z1;
    }
    __syncthreads();

    if (tid < 256) {
      int bl = tid >> 7;
      int b = r0 + bl;
      float xcv = xc_s[bl * 128 + fdot];
      float zh = xh_part[bl * 128 + fdot] + xh_part[256 + bl * 128 + fdot]
               + xh_part[512 + bl * 128 + fdot] + xh_part[768 + bl * 128 + fdot]
               - xcv * wfd_r + bfr_r;
      float ch = fmaf(al, zh, (1.0f - al) * xh_r);
      float cc = fmaf(1.0f - mv, ch, mv * xv);
      size_t ob = (size_t)b * (TT * FF) + (size_t)t * FF + fdot;
      out[ob] = cc;
      out[BTF + ob] = ch;
      out[2 * (size_t)BTF + ob] = zh;
      out[3 * (size_t)BTF + ob] = xh_r;
      ccbf[b * FF + fdot] = f2bf(cc);
    }

    // ---- barrier A: cc ready group-wide ----
    group_barrier(cntA, 32u * (++epA));

    // ---- phase2b: cc K-section (khalf0 waves) + gates publish ----
    if (khalf == 0) {
      const ushort_t* ccrow = ccbf + (size_t)arow * FF + quad * 8;
      bf16x8 AC[4];
#pragma unroll
      for (int kk = 0; kk < 4; ++kk) AC[kk] = *(const bf16x8*)(ccrow + kk * 32);
#pragma unroll
      for (int kk = 0; kk < 4; ++kk) {
#pragma unroll
        for (int nt = 0; nt < 4; ++nt) {
          bf16x8 bv = *(const bf16x8*)(&W_lds[(nt * 16 + lan) * 776 + kk * 32 + quad * 8]);
          acc[nt] = __builtin_amdgcn_mfma_f32_16x16x32_bf16(AC[kk], bv, acc[nt], 0, 0, 0);
        }
      }
#pragma unroll
      for (int nt = 0; nt < 4; ++nt)
#pragma unroll
        for (int r = 0; r < 4; ++r)
          gates_lds[(mt * 16 + quad * 4 + r) * 68 + nt * 16 + lan] = acc[nt][r];
    }
    __syncthreads();

    // ---- LSTM epilogue: c in registers, write h (f32) + pre-decayed h (bf16) ----
    {
      const float* g0 = &gates_lds[(size_t)b_l * 68 + jl0];
      const float* g1 = &gates_lds[(size_t)(64 + b_l) * 68 + jl0];
      float2 gI = make_float2(g0[0] + g1[0] + bias_lds[jl0],
                              g0[1] + g1[1] + bias_lds[jl0 + 1]);
      float2 gF = make_float2(g0[16] + g1[16] + bias_lds[16 + jl0],
                              g0[17] + g1[17] + bias_lds[16 + jl0 + 1]);
      float2 gG = make_float2(g0[32] + g1[32] + bias_lds[32 + jl0],
                              g0[33] + g1[33] + bias_lds[32 + jl0 + 1]);
      float2 gO = make_float2(g0[48] + g1[48] + bias_lds[48 + jl0],
                              g0[49] + g1[49] + bias_lds[48 + jl0 + 1]);
      c_r0 = fmaf(sigm(gF.x), c_r0, sigm(gI.x) * tanhf(gG.x));
      c_r1 = fmaf(sigm(gF.y), c_r1, sigm(gI.y) * tanhf(gG.y));
      float h0 = sigm(gO.x) * tanhf(c_r0);
      float h1 = sigm(gO.y) * tanhf(c_r1);
      float* hwN = hws + (size_t)((t + 1) & 1) * BH;
      ushort_t* hdN = hdws + (size_t)((t + 1) & 1) * BH;
      *(float2*)&hwN[(size_t)bglob * HH + j0] = make_float2(h0, h1);
      float gHa = lo2f(gh2), gHb = hi2f(gh2);
      unsigned hp = ((unsigned)f2bf(h0 * gHa)) | (((unsigned)f2bf(h1 * gHb)) << 16);
      *(unsigned*)&hdN[(size_t)bglob * HH + j0] = hp;
    }

    // ---- barrier B: h / hdec ready group-wide ----
    group_barrier(cntB, 32u * (++epB));
  }
}

// ---------------- host ----------------
extern "C" void kernel_launch(void* const* d_in, const int* in_sizes, int n_in,
                              void* d_out, int out_size, void* d_ws, size_t ws_size,
                              hipStream_t stream) {
  (void)in_sizes; (void)n_in; (void)out_size; (void)ws_size;
  const float* x   = (const float*)d_in[0];
  const int*   mask= (const int*)d_in[1];
  const float* Wdh = (const float*)d_in[2];
  const float* bdh = (const float*)d_in[3];
  const float* Wdx = (const float*)d_in[4];
  const float* bdx = (const float*)d_in[5];
  const float* Wh  = (const float*)d_in[6];
  const float* bh  = (const float*)d_in[7];
  const float* Wf  = (const float*)d_in[8];
  const float* bfr = (const float*)d_in[9];
  const float* Wc  = (const float*)d_in[10];
  const float* bc  = (const float*)d_in[11];
  const float* Wih = (const float*)d_in[12];
  const float* Whh = (const float*)d_in[13];
  const float* bih = (const float*)d_in[14];
  const float* bhh = (const float*)d_in[15];
  float* out = (float*)d_out;
  char* ws = (char*)d_ws;

  hipLaunchKernelGGL(k_cvt,  dim3(1),   dim3(256), 0, stream, Wdx, ws);
  hipLaunchKernelGGL(k_prep, dim3(256), dim3(256), 0, stream, mask, ws);
  hipLaunchKernelGGL(k_gh,   dim3(768, 8), dim3(256), 0, stream, Wdh, bdh, ws);
  hipLaunchKernelGGL(k_al,   dim3(768, 2), dim3(256), 0, stream, Wc, bc, bdx, ws);

  hipFuncSetAttribute((const void*)k_main, hipFuncAttributeMaxDynamicSharedMemorySize, 143616);
  void* args[] = { (void*)&x, (void*)&mask, (void*)&Wh, (void*)&Wf, (void*)&bh, (void*)&bfr,
                   (void*)&Wih, (void*)&Whh, (void*)&bih, (void*)&bhh, (void*)&out, (void*)&ws };
  hipLaunchCooperativeKernel((const void*)k_main, dim3(256), dim3(512), args, 143616, stream);
}

// Round 4
// 1797.309 us; speedup vs baseline: 4.0274x; 1.4764x over previous
//
#include <hip/hip_runtime.h>
#include <cstdint>
#include <cstddef>

// ---------------- problem constants ----------------
#define BB 512
#define TT 96
#define FF 128
#define HH 512
#define BTF 6291456      // B*T*F
#define BH  262144       // B*H

typedef unsigned short ushort_t;
typedef __attribute__((ext_vector_type(8))) short bf16x8;
typedef __attribute__((ext_vector_type(4))) float f32x4;

// ---------------- ws layout (bytes) ----------------
static constexpr size_t OFF_FLAGS = 0;                        // 16 barrier counters, 128 B apart
static constexpr size_t OFF_WDXD  = 2048;                     // f32 [F] diag of Wdx
static constexpr size_t OFF_DELTA = 4096;                     // bf16 [T*B*F]
static constexpr size_t OFF_MBF   = OFF_DELTA + 12582912;     // bf16 [B*T*F]
static constexpr size_t OFF_ALPHA = OFF_MBF   + 12582912;     // bf16 [T*B*F]
static constexpr size_t OFF_GH    = OFF_ALPHA + 12582912;     // bf16 [T*B*H]
static constexpr size_t OFF_H     = OFF_GH    + 50331648;     // f32  [2][B*H] ping-pong
static constexpr size_t OFF_HDEC  = OFF_H     + 2097152;      // bf16 [2][B*H]
static constexpr size_t OFF_CCBF  = OFF_HDEC  + 1048576;      // bf16 [B*F]
// total ~91.4 MB

// ---------------- helpers ----------------
__device__ __forceinline__ float bf2f(ushort_t u) {
  union { unsigned u; float f; } c; c.u = ((unsigned)u) << 16; return c.f;
}
__device__ __forceinline__ ushort_t f2bf(float f) {
  union { float f; unsigned u; } c; c.f = f;
  unsigned x = c.u;
  unsigned r = (x + 0x7FFFu + ((x >> 16) & 1u)) >> 16;
  return (ushort_t)r;
}
__device__ __forceinline__ float lo2f(unsigned p) {
  union { unsigned u; float f; } c; c.u = p << 16; return c.f;
}
__device__ __forceinline__ float hi2f(unsigned p) {
  union { unsigned u; float f; } c; c.u = p & 0xffff0000u; return c.f;
}
__device__ __forceinline__ float sigm(float v) { return 1.0f / (1.0f + __expf(-v)); }

// coherent (device-scope, per-access) helpers: compile to global_load/store sc0 sc1,
// NO wbl2/inv cache maintenance.
__device__ __forceinline__ bf16x8 cload16(const ushort_t* p) {
  union { unsigned long long q[2]; bf16x8 v; } u;
  unsigned long long* a = (unsigned long long*)p;
  u.q[0] = __hip_atomic_load(a,     __ATOMIC_RELAXED, __HIP_MEMORY_SCOPE_AGENT);
  u.q[1] = __hip_atomic_load(a + 1, __ATOMIC_RELAXED, __HIP_MEMORY_SCOPE_AGENT);
  return u.v;
}
__device__ __forceinline__ unsigned long long cload8(const void* p) {
  return __hip_atomic_load((unsigned long long*)p, __ATOMIC_RELAXED, __HIP_MEMORY_SCOPE_AGENT);
}
__device__ __forceinline__ void cstore8(void* p, unsigned long long v) {
  __hip_atomic_store((unsigned long long*)p, v, __ATOMIC_RELAXED, __HIP_MEMORY_SCOPE_AGENT);
}
__device__ __forceinline__ void cstore4(void* p, unsigned v) {
  __hip_atomic_store((unsigned*)p, v, __ATOMIC_RELAXED, __HIP_MEMORY_SCOPE_AGENT);
}
__device__ __forceinline__ void cstore2(ushort_t* p, ushort_t v) {
  __hip_atomic_store(p, v, __ATOMIC_RELAXED, __HIP_MEMORY_SCOPE_AGENT);
}

// ---------------- precompute: flag zero + Wdx diag ----------------
__global__ void k_cvt(const float* __restrict__ Wdx, char* __restrict__ ws) {
  int tid = threadIdx.x;
  unsigned* fl = (unsigned*)(ws + OFF_FLAGS);
  fl[tid] = 0; fl[256 + tid] = 0;
  float* wdxd = (float*)(ws + OFF_WDXD);
  if (tid < FF) wdxd[tid] = Wdx[tid * (FF + 1)];
}

// ---------------- precompute: delta recurrence + m bf16 ----------------
__global__ void k_prep(const int* __restrict__ mask, char* __restrict__ ws) {
  ushort_t* delta = (ushort_t*)(ws + OFF_DELTA);
  ushort_t* mbf   = (ushort_t*)(ws + OFF_MBF);
  int gtid = blockIdx.x * 256 + threadIdx.x;   // 65536 = B*F
  int b = gtid >> 7, f = gtid & 127;
  const int* mrow = mask + (size_t)b * (TT * FF) + f;
  float dprev = 0.0f;
  for (int t = 0; t < TT; ++t) {
    float d;
    if (t == 0) d = 0.0f;
    else {
      int mp = mrow[(t - 1) * FF];
      d = mp ? 1.0f : dprev + 1.0f;
    }
    dprev = d;
    delta[((size_t)t * BB + b) * FF + f] = f2bf(d);
    int mc = mrow[t * FF];
    mbf[(size_t)b * (TT * FF) + t * FF + f] = f2bf((float)mc);
  }
}

// ---------------- precompute: gamma_h = exp(-relu(delta @ Wdh^T + bdh)) ----------------
__global__ __launch_bounds__(256, 4) void k_gh(const float* __restrict__ Wdh,
                                               const float* __restrict__ bdh,
                                               char* __restrict__ ws) {
  __shared__ ushort_t A_lds[64 * 136];
  __shared__ ushort_t B_lds[64 * 136];
  const ushort_t* delta = (const ushort_t*)(ws + OFF_DELTA);
  ushort_t* gh = (ushort_t*)(ws + OFF_GH);
  int tid = threadIdx.x;
  int m0 = blockIdx.x * 64;
  int n0 = blockIdx.y * 64;
  for (int v = tid; v < 1024; v += 256) {
    int row = v >> 4, seg = v & 15;
    *(uint4*)&A_lds[row * 136 + seg * 8] =
        *(const uint4*)(delta + ((size_t)(m0 + row)) * FF + seg * 8);
  }
  for (int v = tid; v < 1024; v += 256) {
    int n = v >> 4, seg = v & 15;
    const float* src = Wdh + (size_t)(n0 + n) * FF + seg * 8;
    ushort_t tmp[8];
#pragma unroll
    for (int j = 0; j < 8; ++j) tmp[j] = f2bf(src[j]);
    *(uint4*)&B_lds[n * 136 + seg * 8] = *(const uint4*)tmp;
  }
  __syncthreads();
  int wave = tid >> 6, lane = tid & 63, quad = lane >> 4, lan = lane & 15;
  int mt = wave;
  f32x4 acc[4];
#pragma unroll
  for (int nt = 0; nt < 4; ++nt) acc[nt] = (f32x4){0.f, 0.f, 0.f, 0.f};
  const ushort_t* ab = &A_lds[(mt * 16 + lan) * 136 + quad * 8];
#pragma unroll
  for (int kk = 0; kk < 4; ++kk) {
    bf16x8 af = *(const bf16x8*)(ab + kk * 32);
#pragma unroll
    for (int nt = 0; nt < 4; ++nt) {
      bf16x8 bfv = *(const bf16x8*)(&B_lds[(nt * 16 + lan) * 136 + kk * 32 + quad * 8]);
      acc[nt] = __builtin_amdgcn_mfma_f32_16x16x32_bf16(af, bfv, acc[nt], 0, 0, 0);
    }
  }
#pragma unroll
  for (int nt = 0; nt < 4; ++nt) {
#pragma unroll
    for (int r = 0; r < 4; ++r) {
      int mg = m0 + mt * 16 + quad * 4 + r;
      int nc = n0 + nt * 16 + lan;
      float v = acc[nt][r] + bdh[nc];
      gh[(size_t)mg * HH + nc] = f2bf(__expf(-fmaxf(v, 0.0f)));
    }
  }
}

// ---------------- precompute: alpha = sigmoid([gamma_x, m] @ Wc^T + bc) ----------------
__global__ __launch_bounds__(256, 4) void k_al(const float* __restrict__ Wc,
                                               const float* __restrict__ bc,
                                               const float* __restrict__ bdx,
                                               char* __restrict__ ws) {
  __shared__ ushort_t A_lds[64 * 136];
  __shared__ ushort_t B_lds[64 * 136];
  const ushort_t* delta = (const ushort_t*)(ws + OFF_DELTA);
  const ushort_t* mbf   = (const ushort_t*)(ws + OFF_MBF);
  const float* wdxd     = (const float*)(ws + OFF_WDXD);
  ushort_t* alpha = (ushort_t*)(ws + OFF_ALPHA);
  int tid = threadIdx.x;
  int m0 = blockIdx.x * 64;
  int n0 = blockIdx.y * 64;
  int wave = tid >> 6, lane = tid & 63, quad = lane >> 4, lan = lane & 15;
  int mt = wave;
  f32x4 acc[4];
#pragma unroll
  for (int nt = 0; nt < 4; ++nt) acc[nt] = (f32x4){0.f, 0.f, 0.f, 0.f};
  for (int c = 0; c < 2; ++c) {
    __syncthreads();
    if (c == 0) {
      for (int v = tid; v < 1024; v += 256) {
        int row = v >> 4, seg = v & 15;
        int mg = m0 + row;
        ushort_t tmp[8];
#pragma unroll
        for (int j = 0; j < 8; ++j) {
          int k = seg * 8 + j;
          float d = bf2f(delta[(size_t)mg * FF + k]);
          float g = __expf(-fmaxf(fmaf(d, wdxd[k], bdx[k]), 0.0f));
          tmp[j] = f2bf(g);
        }
        *(uint4*)&A_lds[row * 136 + seg * 8] = *(const uint4*)tmp;
      }
    } else {
      for (int v = tid; v < 1024; v += 256) {
        int row = v >> 4, seg = v & 15;
        int mg = m0 + row;
        int t = mg >> 9, b = mg & 511;
        *(uint4*)&A_lds[row * 136 + seg * 8] =
            *(const uint4*)(mbf + ((size_t)b * TT + t) * FF + seg * 8);
      }
    }
    for (int v = tid; v < 1024; v += 256) {
      int n = v >> 4, seg = v & 15;
      const float* src = Wc + (size_t)(n0 + n) * 256 + c * 128 + seg * 8;
      ushort_t tmp[8];
#pragma unroll
      for (int j = 0; j < 8; ++j) tmp[j] = f2bf(src[j]);
      *(uint4*)&B_lds[n * 136 + seg * 8] = *(const uint4*)tmp;
    }
    __syncthreads();
    const ushort_t* ab = &A_lds[(mt * 16 + lan) * 136 + quad * 8];
#pragma unroll
    for (int kk = 0; kk < 4; ++kk) {
      bf16x8 af = *(const bf16x8*)(ab + kk * 32);
#pragma unroll
      for (int nt = 0; nt < 4; ++nt) {
        bf16x8 bfv = *(const bf16x8*)(&B_lds[(nt * 16 + lan) * 136 + kk * 32 + quad * 8]);
        acc[nt] = __builtin_amdgcn_mfma_f32_16x16x32_bf16(af, bfv, acc[nt], 0, 0, 0);
      }
    }
  }
#pragma unroll
  for (int nt = 0; nt < 4; ++nt) {
#pragma unroll
    for (int r = 0; r < 4; ++r) {
      int mg = m0 + mt * 16 + quad * 4 + r;
      int nc = n0 + nt * 16 + lan;
      float v = acc[nt][r] + bc[nc];
      alpha[(size_t)mg * FF + nc] = f2bf(sigm(v));
    }
  }
}

// ---------------- split group barrier: relaxed atomics, NO cache-flush fences ------------
// Data coherence is per-access (sc0 sc1 loads/stores of shared arrays), so the barrier
// needs only arrival counting. __syncthreads drains each thread's vmcnt (sc1 stores are
// globally visible once retired) before the arrival add.
__device__ __forceinline__ void bar_arrive(unsigned* cnt) {
  __syncthreads();
  if (threadIdx.x == 0)
    __hip_atomic_fetch_add(cnt, 1u, __ATOMIC_RELAXED, __HIP_MEMORY_SCOPE_AGENT);
}
__device__ __forceinline__ void bar_wait(unsigned* cnt, unsigned target) {
  if (threadIdx.x == 0) {
    while (__hip_atomic_load(cnt, __ATOMIC_RELAXED, __HIP_MEMORY_SCOPE_AGENT) < target)
      __builtin_amdgcn_s_sleep(1);
  }
  __syncthreads();
}

// ---------------- persistent cooperative kernel: 96-step recurrence ----------------
// grid 256 x 512 threads; dyn LDS 143616 B (1 WG/CU).
// Groups of 32 WGs by (wg & 7). Group g owns batch rows 64g..64g+63. Member m = wg>>3:
//   phase1: rows r0 = 64g + 2m (Wh/Wf in registers)
//   phase2: gate col-block ng = m, waves K-split (khalf).
// Cross-WG arrays (hws, hdws, ccbf) are accessed ONLY via relaxed agent atomics.
__global__ __launch_bounds__(512, 2) void k_main(
    const float* __restrict__ x, const int* __restrict__ mask,
    const float* __restrict__ Wh, const float* __restrict__ Wf,
    const float* __restrict__ bh, const float* __restrict__ bfr,
    const float* __restrict__ Wih, const float* __restrict__ Whh,
    const float* __restrict__ bih, const float* __restrict__ bhh,
    float* __restrict__ out, char* __restrict__ ws) {
  extern __shared__ char smem[];
  ushort_t* W_lds    = (ushort_t*)smem;                 // 64 x 776 bf16 = 99328 B
  float* gates_lds   = (float*)(smem + 99328);          // 2 x 64 x 68 f32 = 34816 B
  float* bias_lds    = (float*)(smem + 134144);         // 256 B
  float* h_s         = (float*)(smem + 134400);         // 2 x 512 f32 = 4096 B
  float* xh_part     = (float*)(smem + 138496);         // 4 x 256 f32 = 4096 B
  float* xc_s        = (float*)(smem + 142592);         // 256 f32 = 1024 B

  unsigned* cnts = (unsigned*)(ws + OFF_FLAGS);
  const ushort_t* alpha = (const ushort_t*)(ws + OFF_ALPHA);
  const ushort_t* gh    = (const ushort_t*)(ws + OFF_GH);
  const ushort_t* mbf   = (const ushort_t*)(ws + OFF_MBF);
  float*    hws  = (float*)(ws + OFF_H);
  ushort_t* hdws = (ushort_t*)(ws + OFF_HDEC);
  ushort_t* ccbf = (ushort_t*)(ws + OFF_CCBF);

  const int tid  = threadIdx.x;
  const int wg   = blockIdx.x;
  const int g    = wg & 7;          // group (XCD-locality heuristic only)
  const int mwg  = wg >> 3;         // member 0..31
  const int ng   = mwg;             // gate col-block
  const int wave = tid >> 6, lane = tid & 63, quad = lane >> 4, lan = lane & 15;
  const int mt = wave & 3, khalf = wave >> 2;
  const int r0 = g * 64 + mwg * 2;  // phase1 rows
  const int arow = g * 64 + mt * 16 + lan;   // phase2 A-fragment batch row

  unsigned* cntA = cnts + (g * 2 + 0) * 32;
  unsigned* cntB = cnts + (g * 2 + 1) * 32;

  // ---- init: gate-weight slice -> LDS (bf16) ----
  for (int q = tid; q < 4096; q += 512) {           // Wih: 64 n-rows x 256 k
    int n = q >> 6, kq = (q & 63) * 4;
    int r = (n >> 4) * 512 + ng * 16 + (n & 15);
    float4 v = *(const float4*)(Wih + (size_t)r * 256 + kq);
    ushort_t t4[4] = { f2bf(v.x), f2bf(v.y), f2bf(v.z), f2bf(v.w) };
    *(uint2*)&W_lds[n * 776 + kq] = *(const uint2*)t4;
  }
  for (int q = tid; q < 8192; q += 512) {           // Whh: 64 n-rows x 512 k
    int n = q >> 7, kq = (q & 127) * 4;
    int r = (n >> 4) * 512 + ng * 16 + (n & 15);
    float4 v = *(const float4*)(Whh + (size_t)r * 512 + kq);
    ushort_t t4[4] = { f2bf(v.x), f2bf(v.y), f2bf(v.z), f2bf(v.w) };
    *(uint2*)&W_lds[n * 776 + 256 + kq] = *(const uint2*)t4;
  }
  if (tid < 64) {
    int r = (tid >> 4) * 512 + ng * 16 + (tid & 15);
    bias_lds[tid] = bih[r] + bhh[r];
  }

  // ---- init: Wh / Wf slices -> registers (packed bf16 pairs) ----
  const int fdot = tid & 127, kh = tid >> 7;   // dot mapping (all 512 threads)
  unsigned wh_p[64];
  {
    const float* src = Wh + (size_t)fdot * HH + kh * 128;
#pragma unroll
    for (int i = 0; i < 32; ++i) {
      float4 v = *(const float4*)(src + i * 4);
      wh_p[i * 2]     = ((unsigned)f2bf(v.x)) | (((unsigned)f2bf(v.y)) << 16);
      wh_p[i * 2 + 1] = ((unsigned)f2bf(v.z)) | (((unsigned)f2bf(v.w)) << 16);
    }
  }
  unsigned wf_p[16];
  {
    const float* src = Wf + (size_t)fdot * FF + kh * 32;
#pragma unroll
    for (int i = 0; i < 8; ++i) {
      float4 v = *(const float4*)(src + i * 4);
      wf_p[i * 2]     = ((unsigned)f2bf(v.x)) | (((unsigned)f2bf(v.y)) << 16);
      wf_p[i * 2 + 1] = ((unsigned)f2bf(v.z)) | (((unsigned)f2bf(v.w)) << 16);
    }
  }
  float bh_r = 0.f, bfr_r = 0.f, wfd_r = 0.f;
  if (tid < 256) {
    bh_r  = bh[fdot];
    bfr_r = bfr[fdot];
    wfd_r = bf2f(f2bf(Wf[(size_t)fdot * FF + fdot]));  // matches bf16 dot term exactly
  }

  // ---- init: zero owned state slices (buffer 0, coherent stores) ----
  const int b_l = tid >> 3, jl0 = 2 * (tid & 7);     // epilogue mapping
  const int bglob = g * 64 + b_l, j0 = ng * 16 + jl0;
  cstore8(&hws[(size_t)bglob * HH + j0], 0ull);
  cstore4(&hdws[(size_t)bglob * HH + j0], 0u);
  float c_r0 = 0.f, c_r1 = 0.f;

  unsigned epA = 0, epB = 1;
  bar_arrive(cntB);

  for (int t = 0; t < TT; ++t) {
    // ---- prefetch step-indexed inputs (read-only, normal cached loads) ----
    float xv = 0.f, mv = 0.f, al = 0.f;
    if (tid < 256) {
      int bl = tid >> 7;
      int b = r0 + bl;
      size_t gix = (size_t)b * (TT * FF) + (size_t)t * FF + fdot;
      xv = x[gix];
      mv = (float)mask[gix];
      al = bf2f(alpha[((size_t)t * BB + b) * FF + fdot]);
    }
    unsigned gh2 = 0;
    if (t < TT - 1)
      gh2 = *(const unsigned*)&gh[((size_t)(t + 1) * BB + bglob) * HH + j0];
    bf16x8 A0[4], A1[4], A2[4];
    if (khalf == 0) {                                   // m-chunk: precomputed, cached
      const ushort_t* mrow = mbf + ((size_t)arow * TT + t) * FF + quad * 8;
#pragma unroll
      for (int kk = 0; kk < 4; ++kk) A0[kk] = *(const bf16x8*)(mrow + kk * 32);
    }

    // ---- wait for h/hdec of this step ----
    bar_wait(cntB, 32u * epB);

    // ---- coherent loads: h rows r0,r0+1 -> LDS; hdec A-fragments -> regs ----
    {
      const float* hbuf = hws + (size_t)(t & 1) * BH;
      int rsel = tid >> 8, col = (tid & 255) * 2;
      union { unsigned long long q; float2 f; } hu;
      hu.q = cload8(&hbuf[(size_t)(r0 + rsel) * HH + col]);
      *(float2*)&h_s[rsel * 512 + col] = hu.f;
    }
    {
      const ushort_t* hdec = hdws + (size_t)(t & 1) * BH;
      const ushort_t* hrow = hdec + (size_t)arow * HH + quad * 8;
      if (khalf == 0) {
#pragma unroll
        for (int kk = 0; kk < 4; ++kk) A1[kk] = cload16(hrow + kk * 32);
      } else {
#pragma unroll
        for (int kk = 0; kk < 4; ++kk) A0[kk] = cload16(hrow + 128 + kk * 32);
#pragma unroll
        for (int kk = 0; kk < 4; ++kk) A1[kk] = cload16(hrow + 256 + kk * 32);
#pragma unroll
        for (int kk = 0; kk < 4; ++kk) A2[kk] = cload16(hrow + 384 + kk * 32);
      }
    }
    __syncthreads();

    // ---- phase2a MFMA (K-sections not depending on cc) ----
    f32x4 acc[4];
#pragma unroll
    for (int nt = 0; nt < 4; ++nt) acc[nt] = (f32x4){0.f, 0.f, 0.f, 0.f};
    {
      const int w0 = khalf ? 384 : 128;   // A0: m-chunk (128) or hdec c1 (384)
      const int w1 = khalf ? 512 : 256;   // A1: hdec c0 (256) or c2 (512)
#pragma unroll
      for (int kk = 0; kk < 4; ++kk) {
#pragma unroll
        for (int nt = 0; nt < 4; ++nt) {
          bf16x8 bv = *(const bf16x8*)(&W_lds[(nt * 16 + lan) * 776 + w0 + kk * 32 + quad * 8]);
          acc[nt] = __builtin_amdgcn_mfma_f32_16x16x32_bf16(A0[kk], bv, acc[nt], 0, 0, 0);
        }
      }
#pragma unroll
      for (int kk = 0; kk < 4; ++kk) {
#pragma unroll
        for (int nt = 0; nt < 4; ++nt) {
          bf16x8 bv = *(const bf16x8*)(&W_lds[(nt * 16 + lan) * 776 + w1 + kk * 32 + quad * 8]);
          acc[nt] = __builtin_amdgcn_mfma_f32_16x16x32_bf16(A1[kk], bv, acc[nt], 0, 0, 0);
        }
      }
      if (khalf == 1) {
#pragma unroll
        for (int kk = 0; kk < 4; ++kk) {
#pragma unroll
          for (int nt = 0; nt < 4; ++nt) {
            bf16x8 bv = *(const bf16x8*)(&W_lds[(nt * 16 + lan) * 776 + 640 + kk * 32 + quad * 8]);
            acc[nt] = __builtin_amdgcn_mfma_f32_16x16x32_bf16(A2[kk], bv, acc[nt], 0, 0, 0);
          }
        }
        // khalf1 waves are done: publish partial gates now
#pragma unroll
        for (int nt = 0; nt < 4; ++nt)
#pragma unroll
          for (int r = 0; r < 4; ++r)
            gates_lds[(64 + mt * 16 + quad * 4 + r) * 68 + nt * 16 + lan] = acc[nt][r];
      }
    }

    // ---- phase1: xh dot (register Wh, broadcast h from LDS) ----
    {
      float a0 = 0.f, a1 = 0.f;
      const float* h0p = h_s + kh * 128;
      const float* h1p = h_s + 512 + kh * 128;
#pragma unroll
      for (int i2 = 0; i2 < 16; ++i2) {
        float hb0[8], hb1[8];
        *(float4*)&hb0[0] = *(const float4*)&h0p[i2 * 8];
        *(float4*)&hb0[4] = *(const float4*)&h0p[i2 * 8 + 4];
        *(float4*)&hb1[0] = *(const float4*)&h1p[i2 * 8];
        *(float4*)&hb1[4] = *(const float4*)&h1p[i2 * 8 + 4];
#pragma unroll
        for (int j = 0; j < 4; ++j) {
          unsigned wp = wh_p[i2 * 4 + j];
          float w0 = lo2f(wp), w1 = hi2f(wp);
          a0 = fmaf(w0, hb0[2 * j], a0);
          a0 = fmaf(w1, hb0[2 * j + 1], a0);
          a1 = fmaf(w0, hb1[2 * j], a1);
          a1 = fmaf(w1, hb1[2 * j + 1], a1);
        }
      }
      xh_part[kh * 256 + fdot]       = a0;
      xh_part[kh * 256 + 128 + fdot] = a1;
    }
    __syncthreads();

    float xh_r = 0.f;
    if (tid < 256) {
      int bl = tid >> 7;
      xh_r = xh_part[bl * 128 + fdot] + xh_part[256 + bl * 128 + fdot]
           + xh_part[512 + bl * 128 + fdot] + xh_part[768 + bl * 128 + fdot] + bh_r;
      float xcv = fmaf(1.0f - mv, xh_r, mv * xv);
      xc_s[bl * 128 + fdot] = xcv;
    }
    __syncthreads();

    // ---- z_h dot (register Wf, K split 4 ways) ----
    {
      float z0 = 0.f, z1 = 0.f;
      const float* x0p = xc_s + kh * 32;
      const float* x1p = xc_s + 128 + kh * 32;
#pragma unroll
      for (int i2 = 0; i2 < 4; ++i2) {
        float xb0[8], xb1[8];
        *(float4*)&xb0[0] = *(const float4*)&x0p[i2 * 8];
        *(float4*)&xb0[4] = *(const float4*)&x0p[i2 * 8 + 4];
        *(float4*)&xb1[0] = *(const float4*)&x1p[i2 * 8];
        *(float4*)&xb1[4] = *(const float4*)&x1p[i2 * 8 + 4];
#pragma unroll
        for (int j = 0; j < 4; ++j) {
          unsigned wp = wf_p[i2 * 4 + j];
          float w0 = lo2f(wp), w1 = hi2f(wp);
          z0 = fmaf(w0, xb0[2 * j], z0);
          z0 = fmaf(w1, xb0[2 * j + 1], z0);
          z1 = fmaf(w0, xb1[2 * j], z1);
          z1 = fmaf(w1, xb1[2 * j + 1], z1);
        }
      }
      xh_part[kh * 256 + fdot]       = z0;
      xh_part[kh * 256 + 128 + fdot] = z1;
    }
    __syncthreads();

    float zh = 0.f, ch = 0.f, cc = 0.f;
    if (tid < 256) {
      int bl = tid >> 7;
      int b = r0 + bl;
      float xcv = xc_s[bl * 128 + fdot];
      zh = xh_part[bl * 128 + fdot] + xh_part[256 + bl * 128 + fdot]
         + xh_part[512 + bl * 128 + fdot] + xh_part[768 + bl * 128 + fdot]
         - xcv * wfd_r + bfr_r;
      ch = fmaf(al, zh, (1.0f - al) * xh_r);
      cc = fmaf(1.0f - mv, ch, mv * xv);
      cstore2(&ccbf[b * FF + fdot], f2bf(cc));          // coherent: cross-WG consumed
    }

    // ---- barrier A arrive: cc published ----
    bar_arrive(cntA); ++epA;

    // ---- out[] stores overlap barrier-A latency (host-only consumers) ----
    if (tid < 256) {
      int bl = tid >> 7;
      int b = r0 + bl;
      size_t ob = (size_t)b * (TT * FF) + (size_t)t * FF + fdot;
      out[ob] = cc;
      out[BTF + ob] = ch;
      out[2 * (size_t)BTF + ob] = zh;
      out[3 * (size_t)BTF + ob] = xh_r;
    }

    bar_wait(cntA, 32u * epA);

    // ---- phase2b: cc K-section (khalf0 waves) + gates publish ----
    if (khalf == 0) {
      const ushort_t* ccrow = ccbf + (size_t)arow * FF + quad * 8;
      bf16x8 AC[4];
#pragma unroll
      for (int kk = 0; kk < 4; ++kk) AC[kk] = cload16(ccrow + kk * 32);
#pragma unroll
      for (int kk = 0; kk < 4; ++kk) {
#pragma unroll
        for (int nt = 0; nt < 4; ++nt) {
          bf16x8 bv = *(const bf16x8*)(&W_lds[(nt * 16 + lan) * 776 + kk * 32 + quad * 8]);
          acc[nt] = __builtin_amdgcn_mfma_f32_16x16x32_bf16(AC[kk], bv, acc[nt], 0, 0, 0);
        }
      }
#pragma unroll
      for (int nt = 0; nt < 4; ++nt)
#pragma unroll
        for (int r = 0; r < 4; ++r)
          gates_lds[(mt * 16 + quad * 4 + r) * 68 + nt * 16 + lan] = acc[nt][r];
    }
    __syncthreads();

    // ---- LSTM epilogue: c in registers, write h (f32) + pre-decayed h (bf16), coherent ----
    {
      const float* g0 = &gates_lds[(size_t)b_l * 68 + jl0];
      const float* g1 = &gates_lds[(size_t)(64 + b_l) * 68 + jl0];
      float2 gI = make_float2(g0[0] + g1[0] + bias_lds[jl0],
                              g0[1] + g1[1] + bias_lds[jl0 + 1]);
      float2 gF = make_float2(g0[16] + g1[16] + bias_lds[16 + jl0],
                              g0[17] + g1[17] + bias_lds[16 + jl0 + 1]);
      float2 gG = make_float2(g0[32] + g1[32] + bias_lds[32 + jl0],
                              g0[33] + g1[33] + bias_lds[32 + jl0 + 1]);
      float2 gO = make_float2(g0[48] + g1[48] + bias_lds[48 + jl0],
                              g0[49] + g1[49] + bias_lds[48 + jl0 + 1]);
      c_r0 = fmaf(sigm(gF.x), c_r0, sigm(gI.x) * tanhf(gG.x));
      c_r1 = fmaf(sigm(gF.y), c_r1, sigm(gI.y) * tanhf(gG.y));
      float h0 = sigm(gO.x) * tanhf(c_r0);
      float h1 = sigm(gO.y) * tanhf(c_r1);
      float* hwN = hws + (size_t)((t + 1) & 1) * BH;
      ushort_t* hdN = hdws + (size_t)((t + 1) & 1) * BH;
      union { float2 f; unsigned long long q; } hu; hu.f = make_float2(h0, h1);
      cstore8(&hwN[(size_t)bglob * HH + j0], hu.q);
      float gHa = lo2f(gh2), gHb = hi2f(gh2);
      unsigned hp = ((unsigned)f2bf(h0 * gHa)) | (((unsigned)f2bf(h1 * gHb)) << 16);
      cstore4(&hdN[(size_t)bglob * HH + j0], hp);
    }

    // ---- barrier B arrive: h / hdec published ----
    bar_arrive(cntB); ++epB;
  }
}

// ---------------- host ----------------
extern "C" void kernel_launch(void* const* d_in, const int* in_sizes, int n_in,
                              void* d_out, int out_size, void* d_ws, size_t ws_size,
                              hipStream_t stream) {
  (void)in_sizes; (void)n_in; (void)out_size; (void)ws_size;
  const float* x   = (const float*)d_in[0];
  const int*   mask= (const int*)d_in[1];
  const float* Wdh = (const float*)d_in[2];
  const float* bdh = (const float*)d_in[3];
  const float* Wdx = (const float*)d_in[4];
  const float* bdx = (const float*)d_in[5];
  const float* Wh  = (const float*)d_in[6];
  const float* bh  = (const float*)d_in[7];
  const float* Wf  = (const float*)d_in[8];
  const float* bfr = (const float*)d_in[9];
  const float* Wc  = (const float*)d_in[10];
  const float* bc  = (const float*)d_in[11];
  const float* Wih = (const float*)d_in[12];
  const float* Whh = (const float*)d_in[13];
  const float* bih = (const float*)d_in[14];
  const float* bhh = (const float*)d_in[15];
  float* out = (float*)d_out;
  char* ws = (char*)d_ws;

  hipLaunchKernelGGL(k_cvt,  dim3(1),   dim3(256), 0, stream, Wdx, ws);
  hipLaunchKernelGGL(k_prep, dim3(256), dim3(256), 0, stream, mask, ws);
  hipLaunchKernelGGL(k_gh,   dim3(768, 8), dim3(256), 0, stream, Wdh, bdh, ws);
  hipLaunchKernelGGL(k_al,   dim3(768, 2), dim3(256), 0, stream, Wc, bc, bdx, ws);

  hipFuncSetAttribute((const void*)k_main, hipFuncAttributeMaxDynamicSharedMemorySize, 143616);
  void* args[] = { (void*)&x, (void*)&mask, (void*)&Wh, (void*)&Wf, (void*)&bh, (void*)&bfr,
                   (void*)&Wih, (void*)&Whh, (void*)&bih, (void*)&bhh, (void*)&out, (void*)&ws };
  hipLaunchCooperativeKernel((const void*)k_main, dim3(256), dim3(512), args, 143616, stream);
}